// Round 7
// baseline (481.937 us; speedup 1.0000x reference)
//
#include <hip/hip_runtime.h>

// SpMM out = w[idx] * segment_sum(vals[:,None] * x[cols], rows, N)
// Bucket-binning + LDS-tile gather:
//   memset(ghist) -> hist (LDS per-block) -> scan (1 block) ->
//   bin (LDS-cursor place, ~coalesced 8B records, key = rowbucket*4|colrange)
//   -> gather (block per 64-row bucket, 16KB LDS f32 tile, ds_add_f32,
//              wave-per-edge, unroll-8; contiguous metadata stream).
// R5 lesson: scatter to exact CSR slots = 52.5MB write amplification.
// R6 lesson: linked-list chains = 102MB metadata read amplification.
// This layout keeps BOTH sides line-friendly.

#define FEAT_D 64
#define BROWS 64     // rows per bucket
#define BSHIFT 6
#define NCR 4        // col ranges (col >> 14, valid for N <= 65536)
#define CRSHIFT 14
#define EPB 8192     // edges per hist/bin block
#define BIN_BLOCK 256

__global__ void hist_kernel(const int* __restrict__ edge_rows,
                            const int* __restrict__ edge_cols,
                            const int* __restrict__ idx_ptr,
                            int* __restrict__ ghist, int E, int NBIN) {
    extern __shared__ int lh[];
    const long long off = (long long)idx_ptr[0] * E;
    const int* rows = edge_rows + off;
    const int* cols = edge_cols + off;
    for (int k = threadIdx.x; k < NBIN; k += blockDim.x) lh[k] = 0;
    __syncthreads();
    const int s = blockIdx.x * EPB;
    const int e2 = min(s + EPB, E);
    for (int g = s + threadIdx.x; g < e2; g += blockDim.x) {
        const int key = ((rows[g] >> BSHIFT) << 2) | (cols[g] >> CRSHIFT);
        atomicAdd(&lh[key], 1);
    }
    __syncthreads();
    for (int k = threadIdx.x; k < NBIN; k += blockDim.x)
        if (lh[k]) atomicAdd(&ghist[k], lh[k]);
}

// Single-block scan over NBIN (<=4096) counts -> binoff[0..n] and cursor copy.
__global__ void scan_kernel(const int* __restrict__ counts,
                            int* __restrict__ binoff,
                            int* __restrict__ cursor, int n) {
    __shared__ int part[1024];
    const int tid = threadIdx.x;
    const int per = (n + 1023) >> 10;
    const int s = tid * per;
    const int e2 = min(s + per, n);
    int sum = 0;
    for (int i = s; i < e2; ++i) sum += counts[i];
    part[tid] = sum;
    __syncthreads();
    for (int d = 1; d < 1024; d <<= 1) {
        int add = (tid >= d) ? part[tid - d] : 0;
        __syncthreads();
        part[tid] += add;
        __syncthreads();
    }
    int run = part[tid] - sum;
    for (int i = s; i < e2; ++i) {
        binoff[i] = run;
        cursor[i] = run;
        run += counts[i];
    }
    if (tid == 1023) binoff[n] = part[1023];
}

__global__ void bin_kernel(const float* __restrict__ edge_vals,
                           const int* __restrict__ edge_rows,
                           const int* __restrict__ edge_cols,
                           const int* __restrict__ idx_ptr,
                           int* __restrict__ cursor,
                           int2* __restrict__ pack, int E, int NBIN) {
    extern __shared__ int lh[];
    const long long off = (long long)idx_ptr[0] * E;
    const int* rows = edge_rows + off;
    const int* cols = edge_cols + off;
    const float* vals = edge_vals + off;
    for (int k = threadIdx.x; k < NBIN; k += blockDim.x) lh[k] = 0;
    __syncthreads();
    const int s = blockIdx.x * EPB;
    const int e2 = min(s + EPB, E);
    // phase 1: per-block per-bin counts
    for (int g = s + threadIdx.x; g < e2; g += blockDim.x) {
        const int key = ((rows[g] >> BSHIFT) << 2) | (cols[g] >> CRSHIFT);
        atomicAdd(&lh[key], 1);
    }
    __syncthreads();
    // phase 2: reserve global ranges; lh[k] becomes this block's running cursor
    for (int k = threadIdx.x; k < NBIN; k += blockDim.x) {
        const int c = lh[k];
        if (c) lh[k] = atomicAdd(&cursor[k], c);
    }
    __syncthreads();
    // phase 3: place packed records (col<<6 | row_local, val)
    for (int g = s + threadIdx.x; g < e2; g += blockDim.x) {
        const int r = rows[g], c = cols[g];
        const int key = ((r >> BSHIFT) << 2) | (c >> CRSHIFT);
        const int pos = atomicAdd(&lh[key], 1);
        pack[pos] = make_int2((c << BSHIFT) | (r & (BROWS - 1)),
                              __float_as_int(vals[g]));
    }
}

// Block per bucket: 64x64 f32 LDS tile, wave-per-edge, lane = feature.
__global__ __launch_bounds__(256) void gather_kernel(
        const float* __restrict__ x,
        const float* __restrict__ weight,
        const int* __restrict__ idx_ptr,
        const int* __restrict__ binoff,
        const int2* __restrict__ pack,
        float* __restrict__ out, int N) {
    __shared__ float sacc[BROWS * FEAT_D];  // 16KB
    const int b = blockIdx.x;
    const int t = threadIdx.x;
    const int lane = t & 63;
    const int w4 = t >> 6;  // wave 0..3
    for (int i = t; i < BROWS * FEAT_D; i += 256) sacc[i] = 0.f;
    __syncthreads();
    const int start = binoff[b * NCR];
    const int end = binoff[(b + 1) * NCR];
    int e = start + w4;
    // unroll 8 (stride 4 waves): 8 independent x-row loads in flight per wave
    for (; e + 28 < end; e += 32) {
        const int2 p0 = pack[e];
        const int2 p1 = pack[e + 4];
        const int2 p2 = pack[e + 8];
        const int2 p3 = pack[e + 12];
        const int2 p4 = pack[e + 16];
        const int2 p5 = pack[e + 20];
        const int2 p6 = pack[e + 24];
        const int2 p7 = pack[e + 28];
        const float x0 = x[(p0.x >> BSHIFT) * FEAT_D + lane];
        const float x1 = x[(p1.x >> BSHIFT) * FEAT_D + lane];
        const float x2 = x[(p2.x >> BSHIFT) * FEAT_D + lane];
        const float x3 = x[(p3.x >> BSHIFT) * FEAT_D + lane];
        const float x4 = x[(p4.x >> BSHIFT) * FEAT_D + lane];
        const float x5 = x[(p5.x >> BSHIFT) * FEAT_D + lane];
        const float x6 = x[(p6.x >> BSHIFT) * FEAT_D + lane];
        const float x7 = x[(p7.x >> BSHIFT) * FEAT_D + lane];
        atomicAdd(&sacc[(p0.x & (BROWS - 1)) * FEAT_D + lane], __int_as_float(p0.y) * x0);
        atomicAdd(&sacc[(p1.x & (BROWS - 1)) * FEAT_D + lane], __int_as_float(p1.y) * x1);
        atomicAdd(&sacc[(p2.x & (BROWS - 1)) * FEAT_D + lane], __int_as_float(p2.y) * x2);
        atomicAdd(&sacc[(p3.x & (BROWS - 1)) * FEAT_D + lane], __int_as_float(p3.y) * x3);
        atomicAdd(&sacc[(p4.x & (BROWS - 1)) * FEAT_D + lane], __int_as_float(p4.y) * x4);
        atomicAdd(&sacc[(p5.x & (BROWS - 1)) * FEAT_D + lane], __int_as_float(p5.y) * x5);
        atomicAdd(&sacc[(p6.x & (BROWS - 1)) * FEAT_D + lane], __int_as_float(p6.y) * x6);
        atomicAdd(&sacc[(p7.x & (BROWS - 1)) * FEAT_D + lane], __int_as_float(p7.y) * x7);
    }
    for (; e < end; e += 4) {
        const int2 p = pack[e];
        const float xv = x[(p.x >> BSHIFT) * FEAT_D + lane];
        atomicAdd(&sacc[(p.x & (BROWS - 1)) * FEAT_D + lane], __int_as_float(p.y) * xv);
    }
    __syncthreads();
    const float w = weight[idx_ptr[0]];
    const int row0 = b << BSHIFT;
    for (int i = t; i < BROWS * FEAT_D; i += 256) {
        const int row = row0 + (i >> BSHIFT);
        if (row < N) out[row * FEAT_D + (i & (FEAT_D - 1))] = w * sacc[i];
    }
}

// ---- fallback (direct atomic scatter) ----
__global__ void spmm_scatter_kernel(const float* __restrict__ x,
                                    const float* __restrict__ weight,
                                    const float* __restrict__ edge_vals,
                                    const int* __restrict__ edge_rows,
                                    const int* __restrict__ edge_cols,
                                    const int* __restrict__ idx_ptr,
                                    float* __restrict__ out,
                                    int E, long long work) {
    const int idx = idx_ptr[0];
    const float w = weight[idx];
    const long long rel_off = (long long)idx * E;
    long long t = (long long)blockIdx.x * blockDim.x + threadIdx.x;
    if (t >= work) return;
    const int e = (int)(t >> 4);
    const int q = (int)(t & 15);
    const int r = edge_rows[rel_off + e];
    const int c = edge_cols[rel_off + e];
    const float wv = w * edge_vals[rel_off + e];
    const float4 xv = *reinterpret_cast<const float4*>(x + (long long)c * FEAT_D + q * 4);
    float* op = out + (long long)r * FEAT_D + q * 4;
    atomicAdd(op + 0, wv * xv.x);
    atomicAdd(op + 1, wv * xv.y);
    atomicAdd(op + 2, wv * xv.z);
    atomicAdd(op + 3, wv * xv.w);
}

extern "C" void kernel_launch(void* const* d_in, const int* in_sizes, int n_in,
                              void* d_out, int out_size, void* d_ws, size_t ws_size,
                              hipStream_t stream) {
    const float* x         = (const float*)d_in[0];
    const float* weight    = (const float*)d_in[1];
    const float* edge_vals = (const float*)d_in[2];
    const int*   edge_rows = (const int*)d_in[3];
    const int*   edge_cols = (const int*)d_in[4];
    const int*   idx_ptr   = (const int*)d_in[5];
    float* out = (float*)d_out;

    const int R = in_sizes[1];
    const int E = in_sizes[2] / R;
    const int N = in_sizes[0] / FEAT_D;
    const int NB = (N + BROWS - 1) >> BSHIFT;  // buckets
    const int NBIN = NB * NCR;

    // workspace: pack (8B aligned) | ghist | binoff | cursor
    char* ws = (char*)d_ws;
    size_t o_pack   = 0;
    size_t o_ghist  = o_pack  + (size_t)E * 8;
    size_t o_binoff = o_ghist + (size_t)NBIN * 4;
    size_t o_cursor = o_binoff + (size_t)(NBIN + 1) * 4;
    size_t needed   = o_cursor + (size_t)NBIN * 4;

    if (ws_size < needed || N > 65536 || NBIN > 4096) {
        hipMemsetAsync(d_out, 0, (size_t)out_size * sizeof(float), stream);
        const long long work = (long long)E * 16;
        const int block = 256;
        const long long grid = (work + block - 1) / block;
        spmm_scatter_kernel<<<dim3((unsigned)grid), dim3(block), 0, stream>>>(
            x, weight, edge_vals, edge_rows, edge_cols, idx_ptr, out, E, work);
        return;
    }

    int2* pack   = (int2*)(ws + o_pack);
    int*  ghist  = (int*)(ws + o_ghist);
    int*  binoff = (int*)(ws + o_binoff);
    int*  cursor = (int*)(ws + o_cursor);

    const int HB = (E + EPB - 1) / EPB;
    const size_t lds_bytes = (size_t)NBIN * 4;

    hipMemsetAsync(ghist, 0, (size_t)NBIN * 4, stream);
    hist_kernel<<<HB, BIN_BLOCK, lds_bytes, stream>>>(edge_rows, edge_cols,
                                                      idx_ptr, ghist, E, NBIN);
    scan_kernel<<<1, 1024, 0, stream>>>(ghist, binoff, cursor, NBIN);
    bin_kernel<<<HB, BIN_BLOCK, lds_bytes, stream>>>(edge_vals, edge_rows,
                                                     edge_cols, idx_ptr,
                                                     cursor, pack, E, NBIN);
    gather_kernel<<<NB, 256, 0, stream>>>(x, weight, idx_ptr, binoff, pack,
                                          out, N);
}

// Round 8
// 150.488 us; speedup vs baseline: 3.2025x; 3.2025x over previous
//
#include <hip/hip_runtime.h>

// SpMM out = w[idx] * segment_sum(vals[:,None] * x[cols], rows, N)
//
// R5 lesson: exact-CSR scatter = 52.5MB write amp (60us). R6 lesson: linked
// lists = 102MB read amp. R7 lesson: few-block LDS-atomic gather = parallelism
// collapse (345us, latency-bound even when L3-warm).
//
// This round: fixed-capacity 32-row bucket binning (LDS-clustered writes,
// ~1.3x amp), then gather with 12.5k waves doing REGISTER accumulation:
// block per bucket stages records to LDS, lane-parallel scan sorts them into
// per-(wave,row) LDS lists, wave accumulates 4 rows with unroll-4 MLP.
// Overflow (statistically ~impossible for uniform rows) goes to a global
// list handled by a final fixup kernel -> always correct.

#define FEAT_D 64
#define BROWS 32
#define BSH 5
#define LCAP 40        // per-row LDS list capacity (max expected degree ~35)
#define OVFCAP 16384
#define EPB 8192       // edges per build block
#define BBLOCK 512
#define GBLOCK 512     // 8 waves -> 4 rows/wave

// ---------- build: two-phase LDS-cursor binning into bucket regions ----------
__global__ void build_kernel(const float* __restrict__ edge_vals,
                             const int* __restrict__ edge_rows,
                             const int* __restrict__ edge_cols,
                             const int* __restrict__ idx_ptr,
                             int* __restrict__ bktcnt,
                             int2* __restrict__ pack,
                             int* __restrict__ ovfcnt,
                             int4* __restrict__ ovfbuf,
                             int E, int NBKT, int cap) {
    extern __shared__ int lh[];   // NBKT counters
    const long long off = (long long)idx_ptr[0] * E;
    const int* rows = edge_rows + off;
    const int* cols = edge_cols + off;
    const float* vals = edge_vals + off;
    for (int k = threadIdx.x; k < NBKT; k += blockDim.x) lh[k] = 0;
    __syncthreads();
    const int s = blockIdx.x * EPB;
    const int e2 = min(s + EPB, E);
    // phase 1: local per-bucket counts
    for (int g = s + threadIdx.x; g < e2; g += blockDim.x)
        atomicAdd(&lh[rows[g] >> BSH], 1);
    __syncthreads();
    // phase 2: reserve disjoint global runs; lh[k] becomes this block's cursor
    for (int k = threadIdx.x; k < NBKT; k += blockDim.x) {
        const int c = lh[k];
        if (c) lh[k] = atomicAdd(&bktcnt[k], c);
    }
    __syncthreads();
    // phase 3: place records (col<<5 | row_local, val) -> contiguous runs
    for (int g = s + threadIdx.x; g < e2; g += blockDim.x) {
        const int r = rows[g], c = cols[g];
        const int b = r >> BSH;
        const int pos = atomicAdd(&lh[b], 1);
        if (pos < cap) {
            pack[(long long)b * cap + pos] =
                make_int2((c << BSH) | (r & (BROWS - 1)), __float_as_int(vals[g]));
        } else {
            const int o = atomicAdd(ovfcnt, 1);
            if (o < OVFCAP) ovfbuf[o] = make_int4(r, c, __float_as_int(vals[g]), 0);
        }
    }
}

// ---------- gather: block per bucket, register accumulation ----------
__global__ __launch_bounds__(GBLOCK) void gather_kernel(
        const float* __restrict__ x,
        const float* __restrict__ weight,
        const int* __restrict__ idx_ptr,
        const int* __restrict__ bktcnt,
        const int2* __restrict__ pack,
        int* __restrict__ ovfcnt, int4* __restrict__ ovfbuf,
        float* __restrict__ out, int N, int cap) {
    extern __shared__ int2 sh2[];       // [cap] raw records + [32*LCAP] lists
    int2* sraw = sh2;
    int2* slist = sh2 + cap;
    __shared__ int scur[32];
    const int b = blockIdx.x;
    const int t = threadIdx.x;
    const int w = t >> 6;               // wave 0..7 owns rows 4w..4w+3
    const int lane = t & 63;
    if (t < 32) scur[t] = 0;
    const int cnt = min(bktcnt[b], cap);
    for (int i = t; i < cnt; i += GBLOCK)
        sraw[i] = pack[(long long)b * cap + i];
    __syncthreads();
    // lane-parallel scan: each wave filters all records for its 4 rows
    for (int j = lane; j < cnt; j += 64) {
        const int2 rec = sraw[j];
        const int rl = rec.x & (BROWS - 1);
        if ((rl >> 2) == w) {
            const int q = rl & 3;
            const int li = atomicAdd(&scur[w * 4 + q], 1);
            if (li < LCAP) {
                slist[(w * 4 + q) * LCAP + li] = rec;
            } else {
                const int o = atomicAdd(ovfcnt, 1);
                const int row = (b << BSH) | rl;
                if (o < OVFCAP) ovfbuf[o] = make_int4(row, rec.x >> BSH, rec.y, 0);
            }
        }
    }
    __syncthreads();
    const float wscale = weight[idx_ptr[0]];
    const int base = w * 4;
    float acc0 = 0.f, acc1 = 0.f, acc2 = 0.f, acc3 = 0.f;
#define ROWACC(Q, ACC)                                                        \
    {                                                                         \
        const int n = min(scur[base + Q], LCAP);                              \
        const int2* lp = slist + (base + Q) * LCAP;                           \
        int j = 0;                                                            \
        for (; j + 4 <= n; j += 4) {                                          \
            const int2 r0 = lp[j], r1 = lp[j + 1], r2 = lp[j + 2],            \
                       r3 = lp[j + 3];                                        \
            const float x0 = x[(r0.x >> BSH) * FEAT_D + lane];                \
            const float x1 = x[(r1.x >> BSH) * FEAT_D + lane];                \
            const float x2 = x[(r2.x >> BSH) * FEAT_D + lane];                \
            const float x3 = x[(r3.x >> BSH) * FEAT_D + lane];                \
            ACC += __int_as_float(r0.y) * x0 + __int_as_float(r1.y) * x1 +    \
                   __int_as_float(r2.y) * x2 + __int_as_float(r3.y) * x3;     \
        }                                                                     \
        for (; j < n; ++j) {                                                  \
            const int2 r0 = lp[j];                                            \
            ACC += __int_as_float(r0.y) * x[(r0.x >> BSH) * FEAT_D + lane];   \
        }                                                                     \
    }
    ROWACC(0, acc0)
    ROWACC(1, acc1)
    ROWACC(2, acc2)
    ROWACC(3, acc3)
#undef ROWACC
    const int row0 = (b << BSH) + base;
    if (row0 + 0 < N) out[(long long)(row0 + 0) * FEAT_D + lane] = wscale * acc0;
    if (row0 + 1 < N) out[(long long)(row0 + 1) * FEAT_D + lane] = wscale * acc1;
    if (row0 + 2 < N) out[(long long)(row0 + 2) * FEAT_D + lane] = wscale * acc2;
    if (row0 + 3 < N) out[(long long)(row0 + 3) * FEAT_D + lane] = wscale * acc3;
}

// ---------- fixup: apply overflow records (normally zero work) ----------
__global__ void fixup_kernel(const float* __restrict__ x,
                             const float* __restrict__ weight,
                             const int* __restrict__ idx_ptr,
                             const int* __restrict__ ovfcnt,
                             const int4* __restrict__ ovfbuf,
                             float* __restrict__ out) {
    const int n = min(*ovfcnt, OVFCAP);
    if (n == 0) return;
    const float ws = weight[idx_ptr[0]];
    const int gw = (int)((blockIdx.x * (long long)blockDim.x + threadIdx.x) >> 6);
    const int lane = threadIdx.x & 63;
    const int nw = (gridDim.x * blockDim.x) >> 6;
    for (int r = gw; r < n; r += nw) {
        const int4 rec = ovfbuf[r];
        atomicAdd(&out[(long long)rec.x * FEAT_D + lane],
                  ws * __int_as_float(rec.z) * x[(long long)rec.y * FEAT_D + lane]);
    }
}

// ---------- fallback (direct atomic scatter, always correct) ----------
__global__ void spmm_scatter_kernel(const float* __restrict__ x,
                                    const float* __restrict__ weight,
                                    const float* __restrict__ edge_vals,
                                    const int* __restrict__ edge_rows,
                                    const int* __restrict__ edge_cols,
                                    const int* __restrict__ idx_ptr,
                                    float* __restrict__ out,
                                    int E, long long work) {
    const int idx = idx_ptr[0];
    const float w = weight[idx];
    const long long rel_off = (long long)idx * E;
    long long t = (long long)blockIdx.x * blockDim.x + threadIdx.x;
    if (t >= work) return;
    const int e = (int)(t >> 4);
    const int q = (int)(t & 15);
    const int r = edge_rows[rel_off + e];
    const int c = edge_cols[rel_off + e];
    const float wv = w * edge_vals[rel_off + e];
    const float4 xv = *reinterpret_cast<const float4*>(x + (long long)c * FEAT_D + q * 4);
    float* op = out + (long long)r * FEAT_D + q * 4;
    atomicAdd(op + 0, wv * xv.x);
    atomicAdd(op + 1, wv * xv.y);
    atomicAdd(op + 2, wv * xv.z);
    atomicAdd(op + 3, wv * xv.w);
}

extern "C" void kernel_launch(void* const* d_in, const int* in_sizes, int n_in,
                              void* d_out, int out_size, void* d_ws, size_t ws_size,
                              hipStream_t stream) {
    const float* x         = (const float*)d_in[0];
    const float* weight    = (const float*)d_in[1];
    const float* edge_vals = (const float*)d_in[2];
    const int*   edge_rows = (const int*)d_in[3];
    const int*   edge_cols = (const int*)d_in[4];
    const int*   idx_ptr   = (const int*)d_in[5];
    float* out = (float*)d_out;

    const int R = in_sizes[1];
    const int E = in_sizes[2] / R;
    const int N = in_sizes[0] / FEAT_D;
    const int NBKT = (N + BROWS - 1) >> BSH;

    // ws layout: bktcnt[NBKT] | ovfcnt | pad | ovfbuf[OVFCAP]x16B | pack
    char* ws = (char*)d_ws;
    size_t o_bktcnt = 0;
    size_t o_ovfcnt = o_bktcnt + (size_t)NBKT * 4;
    size_t o_ovfbuf = ((o_ovfcnt + 4 + 15) / 16) * 16;
    size_t o_pack   = o_ovfbuf + (size_t)OVFCAP * 16;
    const size_t room = (ws_size > o_pack) ? (ws_size - o_pack) : 0;
    int cap = (int)(room / ((size_t)NBKT * 8));
    if (cap > 1024) cap = 1024;

    // need cap comfortably above mean bucket load (E/NBKT); else fallback
    const long long meanload = (NBKT > 0) ? ((long long)E / NBKT) : 0;
    if (cap < 64 || cap < meanload + (meanload >> 3) + 16 || NBKT > 8192) {
        hipMemsetAsync(d_out, 0, (size_t)out_size * sizeof(float), stream);
        const long long work = (long long)E * 16;
        const int block = 256;
        const long long grid = (work + block - 1) / block;
        spmm_scatter_kernel<<<dim3((unsigned)grid), dim3(block), 0, stream>>>(
            x, weight, edge_vals, edge_rows, edge_cols, idx_ptr, out, E, work);
        return;
    }

    int*  bktcnt = (int*)(ws + o_bktcnt);
    int*  ovfcnt = (int*)(ws + o_ovfcnt);
    int4* ovfbuf = (int4*)(ws + o_ovfbuf);
    int2* pack   = (int2*)(ws + o_pack);

    // one memset covers bktcnt + ovfcnt (contiguous)
    hipMemsetAsync(bktcnt, 0, (size_t)NBKT * 4 + 4, stream);

    const int bgrid = (E + EPB - 1) / EPB;
    const size_t blds = (size_t)NBKT * 4;
    build_kernel<<<bgrid, BBLOCK, blds, stream>>>(edge_vals, edge_rows,
                                                  edge_cols, idx_ptr, bktcnt,
                                                  pack, ovfcnt, ovfbuf,
                                                  E, NBKT, cap);

    const size_t glds = ((size_t)cap + 32 * LCAP) * 8;
    gather_kernel<<<NBKT, GBLOCK, glds, stream>>>(x, weight, idx_ptr, bktcnt,
                                                  pack, ovfcnt, ovfbuf,
                                                  out, N, cap);

    fixup_kernel<<<64, 256, 0, stream>>>(x, weight, idx_ptr, ovfcnt, ovfbuf, out);
}